// Round 11
// baseline (115.617 us; speedup 1.0000x reference)
//
#include <hip/hip_runtime.h>
#include <stdint.h>

#define NRAYS 2048
#define SMAX  192
#define RESG  128
#define STEPF 0.027f
#define ERTF  1e-4f

typedef __attribute__((ext_vector_type(8)))  short bf16x8;   // 8 bf16 = 4 VGPR
typedef __attribute__((ext_vector_type(16))) float f32x16;   // MFMA 32x32 acc

// ---- bf16 helpers (RNE) ----
__device__ __forceinline__ uint32_t f2b(float x) {
    uint32_t u = __builtin_bit_cast(uint32_t, x);
    return (u + 0x7fffu + ((u >> 16) & 1u)) >> 16;
}
__device__ __forceinline__ uint32_t bpack(float lo, float hi) {
    return f2b(lo) | (f2b(hi) << 16);
}

// ---------------- ray/aabb ----------------
__device__ __forceinline__ void ray_aabb(float ox, float oy, float oz,
                                         float dx, float dy, float dz,
                                         float& tn, float& tf) {
    float ix = 1.0f / ((fabsf(dx) < 1e-9f) ? 1e-9f : dx);
    float iy = 1.0f / ((fabsf(dy) < 1e-9f) ? 1e-9f : dy);
    float iz = 1.0f / ((fabsf(dz) < 1e-9f) ? 1e-9f : dz);
    float t0x = (-1.5f - ox) * ix, t1x = (1.5f - ox) * ix;
    float t0y = (-1.5f - oy) * iy, t1y = (1.5f - oy) * iy;
    float t0z = (-1.5f - oz) * iz, t1z = (1.5f - oz) * iz;
    float tnx = fminf(t0x, t1x), tfx = fmaxf(t0x, t1x);
    float tny = fminf(t0y, t1y), tfy = fmaxf(t0y, t1y);
    float tnz = fminf(t0z, t1z), tfz = fmaxf(t0z, t1z);
    tn = fmaxf(fmaxf(fmaxf(tnx, tny), tnz), 0.0f);
    tf = fminf(fminf(tfx, tfy), tfz);
}

// =================================================================
// Single fused kernel: 256 blocks x 512 threads; block b owns rays
// 8b..8b+7 (wave w -> ray 8b+w). Phases (all block-local, LDS only):
//   0: weight frags W->VGPR (22 x bf16x8 per lane, oc=wave&3)
//   1: march: per-wave ballot masks -> LDS sample list (u16: w<<8|s),
//      per-ray pe_d computed ONCE into sPD
//   2: 128-sample MFMA tiles (PE -> L0 -> L1 -> L2 -> heads -> rgbaL)
//   3: per-wave compositing of its own ray from rgbaL
// =================================================================
__global__ __launch_bounds__(512) void k_fused(
        const float* __restrict__ ro, const float* __restrict__ rd,
        const int* __restrict__ occ,
        const float* __restrict__ W0, const float* __restrict__ W1,
        const float* __restrict__ wsig, const float* __restrict__ W2,
        const float* __restrict__ wrgb, float* __restrict__ out) {
    __shared__ __align__(16) short actA[128 * 128];   // 32KB, rowB=256B
    __shared__ __align__(16) short bufB[128 * 256];   // 64KB, rowB=512B
    __shared__ float4 rgbaL[8 * SMAX];                // 24KB
    __shared__ unsigned short sList[8 * SMAX];        // 3KB  (w<<8 | s)
    __shared__ float  sPD[8][28];                     // per-ray viewdir PE
    __shared__ float  sRD[8][8];                      // ox oy oz dx dy dz tn
    __shared__ float  sV[128];
    __shared__ float  sR[384];
    __shared__ int    sCnt[8];

    const int tid  = threadIdx.x;
    const int wave = tid >> 6;
    const int lane = tid & 63;
    const int oc   = wave & 3;
    const int sc   = wave >> 2;
    const int lo5  = lane & 31;
    const int hi5  = lane >> 5;

    if (tid < 128) sV[tid] = wsig[tid];
    if (tid >= 128 && tid < 512) sR[tid - 128] = wrgb[tid - 128];

    // ---- phase 0: weight fragments direct from global (L2-resident) ----
    bf16x8 wf[22];
    {
        const int outc = oc * 32 + lo5;
        #pragma unroll
        for (int g = 0; g < 22; ++g) {
            const float* W; int kbase, Klim;
            if (g < 4)       { W = W0; kbase = g * 16;        Klim = 63;  }
            else if (g < 12) { W = W1; kbase = (g - 4) * 16;  Klim = 128; }
            else             { W = W2; kbase = (g - 12) * 16; Klim = 155; }
            uint32_t d[4];
            #pragma unroll
            for (int h = 0; h < 4; ++h) {
                int k0 = kbase + (hi5 << 3) + h * 2;
                float lo = (k0     < Klim) ? W[(size_t)k0 * 128 + outc]       : 0.0f;
                float hi = (k0 + 1 < Klim) ? W[(size_t)(k0 + 1) * 128 + outc] : 0.0f;
                d[h] = bpack(lo, hi);
            }
            uint4 v = make_uint4(d[0], d[1], d[2], d[3]);
            wf[g] = __builtin_bit_cast(bf16x8, v);
        }
    }

    // ---- phase 1: march this wave's ray ----
    const int r = blockIdx.x * 8 + wave;
    const float ox = ro[r*3+0], oy = ro[r*3+1], oz = ro[r*3+2];
    const float dx = rd[r*3+0], dy = rd[r*3+1], dz = rd[r*3+2];
    float tn, tf;
    ray_aabb(ox, oy, oz, dx, dy, dz, tn, tf);
    unsigned long long msk[3];
    int myCnt = 0;
    #pragma unroll
    for (int c = 0; c < 3; ++c) {
        int s = c * 64 + lane;
        float t_mid = (tn + STEPF * (float)s) + 0.5f * STEPF;
        bool inside = (t_mid < tf) && (tf > tn);
        bool act = false;
        if (inside) {
            float px = ox + dx * t_mid;
            float py = oy + dy * t_mid;
            float pz = oz + dz * t_mid;
            int gx = min(max((int)((px + 1.5f) / 3.0f * 128.0f), 0), RESG - 1);
            int gy = min(max((int)((py + 1.5f) / 3.0f * 128.0f), 0), RESG - 1);
            int gz = min(max((int)((pz + 1.5f) / 3.0f * 128.0f), 0), RESG - 1);
            act = occ[(gx * RESG + gy) * RESG + gz] != 0;
        }
        unsigned long long mb = __ballot(act);
        msk[c] = mb;
        myCnt += __popcll(mb);
    }
    if (lane == 0) {
        sCnt[wave] = myCnt;
        sRD[wave][0] = ox; sRD[wave][1] = oy; sRD[wave][2] = oz;
        sRD[wave][3] = dx; sRD[wave][4] = dy; sRD[wave][5] = dz;
        sRD[wave][6] = tn;
    }
    if (lane < 28) {        // per-ray viewdir PE (27 used, [27]=0)
        float val = 0.0f;
        if (lane < 3) val = (lane == 0) ? dx : ((lane == 1) ? dy : dz);
        else if (lane < 27) {
            int cc = lane - 3, l = cc / 6, jj = cc - 6 * l;
            int a3 = (jj >= 3) ? jj - 3 : jj;
            float comp = (a3 == 0) ? dx : ((a3 == 1) ? dy : dz);
            float arg = comp * (float)(1 << l);
            val = (jj < 3) ? __sinf(arg) : __cosf(arg);
        }
        sPD[wave][lane] = val;
    }
    __syncthreads();

    int myBase = 0, total = 0;
    #pragma unroll
    for (int i = 0; i < 8; ++i) {
        int ci = sCnt[i];
        if (i < wave) myBase += ci;
        total += ci;
    }
    {   // write this ray's compact entries
        int run = myBase;
        #pragma unroll
        for (int c = 0; c < 3; ++c) {
            unsigned long long mb = msk[c];
            if ((mb >> lane) & 1ull) {
                int within = __popcll(mb & ((1ull << lane) - 1ull));
                sList[run + within] = (unsigned short)((wave << 8) | (c * 64 + lane));
            }
            run += __popcll(mb);
        }
    }
    __syncthreads();

    // ---- phase 2: MFMA tiles over the block's sample list ----
    const int ntiles = (total + 127) >> 7;
    const int mrow   = sc * 64 + lo5;
    const int rswz   = (mrow & 15) << 4;

    for (int t = 0; t < ntiles; ++t) {
        const int base = t << 7;
        __syncthreads();     // protect actA/bufB from previous heads reads

        // ---- PE: 4 threads/sample ----
        {
            int m = tid >> 2, p = tid & 3;
            int gi = base + m;
            float px = 0.f, py = 0.f, pz = 0.f;
            int we = 0;
            if (gi < total) {
                int e = sList[gi];
                we = e >> 8;
                int s = e & 255;
                float tnw = sRD[we][6];
                float t_mid = (tnw + STEPF * (float)s) + 0.5f * STEPF;
                px = sRD[we][0] + sRD[we][3] * t_mid;
                py = sRD[we][1] + sRD[we][4] * t_mid;
                pz = sRD[we][2] + sRD[we][5] * t_mid;
            }
            int swz = (m & 15) << 4;
            #pragma unroll
            for (int half = 0; half < 2; ++half) {
                uint32_t dw[4];
                #pragma unroll
                for (int jp = 0; jp < 4; ++jp) {
                    float v[2];
                    #pragma unroll
                    for (int q = 0; q < 2; ++q) {
                        int c = p * 16 + half * 8 + jp * 2 + q;
                        float val;
                        if (c < 3)        val = (c == 0) ? px : ((c == 1) ? py : pz);
                        else if (c >= 63) val = 0.0f;
                        else {
                            int cc = c - 3, l = cc / 6, jj = cc - 6 * l;
                            int a3 = (jj >= 3) ? jj - 3 : jj;
                            float comp = (a3 == 0) ? px : ((a3 == 1) ? py : pz);
                            float arg = comp * (float)(1 << l);
                            val = (jj < 3) ? __sinf(arg) : __cosf(arg);
                        }
                        v[q] = val;
                    }
                    dw[jp] = bpack(v[0], v[1]);
                }
                *(uint4*)((char*)actA + m * 256 + ((p * 32 + half * 16) ^ swz)) = make_uint4(dw[0], dw[1], dw[2], dw[3]);
            }
            {   // pe_d: copy from per-ray cache
                uint32_t dw[4];
                #pragma unroll
                for (int jp = 0; jp < 4; ++jp) {
                    float v[2];
                    #pragma unroll
                    for (int q = 0; q < 2; ++q) {
                        int c = p * 8 + jp * 2 + q;     // 0..31
                        v[q] = (c < 28) ? sPD[we][c] : 0.0f;
                    }
                    dw[jp] = bpack(v[0], v[1]);
                }
                *(uint4*)((char*)bufB + m * 512 + ((256 + p * 16) ^ swz)) = make_uint4(dw[0], dw[1], dw[2], dw[3]);
            }
        }
        __syncthreads();

        // ---- L0: h_a = relu(pe_p @ W0) -> bufB cols 0..127 ----
        {
            f32x16 a0 = {}, a1 = {};
            #pragma unroll
            for (int kb = 0; kb < 4; ++kb) {
                int cb = (kb * 32 + (hi5 << 4)) ^ rswz;
                bf16x8 b0 = *(const bf16x8*)((const char*)actA + mrow * 256 + cb);
                bf16x8 b1 = *(const bf16x8*)((const char*)actA + (mrow + 32) * 256 + cb);
                a0 = __builtin_amdgcn_mfma_f32_32x32x16_bf16(wf[kb], b0, a0, 0, 0, 0);
                a1 = __builtin_amdgcn_mfma_f32_32x32x16_bf16(wf[kb], b1, a1, 0, 0, 0);
            }
            #pragma unroll
            for (int g = 0; g < 4; ++g) {
                int outb = (oc * 32 + g * 8 + (hi5 << 2)) * 2;
                *(uint2*)((char*)bufB + mrow * 512 + (outb ^ rswz)) =
                    make_uint2(bpack(fmaxf(a0[g*4+0],0.f), fmaxf(a0[g*4+1],0.f)),
                               bpack(fmaxf(a0[g*4+2],0.f), fmaxf(a0[g*4+3],0.f)));
                *(uint2*)((char*)bufB + (mrow + 32) * 512 + (outb ^ rswz)) =
                    make_uint2(bpack(fmaxf(a1[g*4+0],0.f), fmaxf(a1[g*4+1],0.f)),
                               bpack(fmaxf(a1[g*4+2],0.f), fmaxf(a1[g*4+3],0.f)));
            }
        }
        __syncthreads();

        // ---- L1: h_b = relu(h_a @ W1) -> actA ----
        {
            f32x16 a0 = {}, a1 = {};
            #pragma unroll
            for (int kb = 0; kb < 8; ++kb) {
                int cb = (kb * 32 + (hi5 << 4)) ^ rswz;
                bf16x8 b0 = *(const bf16x8*)((const char*)bufB + mrow * 512 + cb);
                bf16x8 b1 = *(const bf16x8*)((const char*)bufB + (mrow + 32) * 512 + cb);
                a0 = __builtin_amdgcn_mfma_f32_32x32x16_bf16(wf[4 + kb], b0, a0, 0, 0, 0);
                a1 = __builtin_amdgcn_mfma_f32_32x32x16_bf16(wf[4 + kb], b1, a1, 0, 0, 0);
            }
            #pragma unroll
            for (int g = 0; g < 4; ++g) {
                int outb = (oc * 32 + g * 8 + (hi5 << 2)) * 2;
                *(uint2*)((char*)actA + mrow * 256 + (outb ^ rswz)) =
                    make_uint2(bpack(fmaxf(a0[g*4+0],0.f), fmaxf(a0[g*4+1],0.f)),
                               bpack(fmaxf(a0[g*4+2],0.f), fmaxf(a0[g*4+3],0.f)));
                *(uint2*)((char*)actA + (mrow + 32) * 256 + (outb ^ rswz)) =
                    make_uint2(bpack(fmaxf(a1[g*4+0],0.f), fmaxf(a1[g*4+1],0.f)),
                               bpack(fmaxf(a1[g*4+2],0.f), fmaxf(a1[g*4+3],0.f)));
            }
        }
        __syncthreads();

        // ---- L2: h2 = relu([h_b | pe_d] @ W2) -> bufB cols 0..127 ----
        {
            f32x16 a0 = {}, a1 = {};
            #pragma unroll
            for (int kb = 0; kb < 8; ++kb) {
                int cb = (kb * 32 + (hi5 << 4)) ^ rswz;
                bf16x8 b0 = *(const bf16x8*)((const char*)actA + mrow * 256 + cb);
                bf16x8 b1 = *(const bf16x8*)((const char*)actA + (mrow + 32) * 256 + cb);
                a0 = __builtin_amdgcn_mfma_f32_32x32x16_bf16(wf[12 + kb], b0, a0, 0, 0, 0);
                a1 = __builtin_amdgcn_mfma_f32_32x32x16_bf16(wf[12 + kb], b1, a1, 0, 0, 0);
            }
            #pragma unroll
            for (int kb = 8; kb < 10; ++kb) {
                int cb = (kb * 32 + (hi5 << 4)) ^ rswz;
                bf16x8 b0 = *(const bf16x8*)((const char*)bufB + mrow * 512 + cb);
                bf16x8 b1 = *(const bf16x8*)((const char*)bufB + (mrow + 32) * 512 + cb);
                a0 = __builtin_amdgcn_mfma_f32_32x32x16_bf16(wf[12 + kb], b0, a0, 0, 0, 0);
                a1 = __builtin_amdgcn_mfma_f32_32x32x16_bf16(wf[12 + kb], b1, a1, 0, 0, 0);
            }
            #pragma unroll
            for (int g = 0; g < 4; ++g) {
                int outb = (oc * 32 + g * 8 + (hi5 << 2)) * 2;
                *(uint2*)((char*)bufB + mrow * 512 + (outb ^ rswz)) =
                    make_uint2(bpack(fmaxf(a0[g*4+0],0.f), fmaxf(a0[g*4+1],0.f)),
                               bpack(fmaxf(a0[g*4+2],0.f), fmaxf(a0[g*4+3],0.f)));
                *(uint2*)((char*)bufB + (mrow + 32) * 512 + (outb ^ rswz)) =
                    make_uint2(bpack(fmaxf(a1[g*4+0],0.f), fmaxf(a1[g*4+1],0.f)),
                               bpack(fmaxf(a1[g*4+2],0.f), fmaxf(a1[g*4+3],0.f)));
            }
        }
        __syncthreads();

        // ---- heads: sigma = h_b @ wsig ; rgb = sigmoid(h2 @ wrgb) ----
        {
            int m = tid >> 2, p = tid & 3;
            int gi = base + m;
            int swz = (m & 15) << 4;
            float sp = 0.f, r0 = 0.f, r1 = 0.f, r2 = 0.f;
            #pragma unroll
            for (int hh = 0; hh < 4; ++hh) {
                uint4 q = *(const uint4*)((const char*)actA + m * 256 + ((p * 64 + hh * 16) ^ swz));
                uint32_t w[4] = {q.x, q.y, q.z, q.w};
                #pragma unroll
                for (int e = 0; e < 4; ++e) {
                    int j = p * 32 + hh * 8 + e * 2;
                    float a0 = __builtin_bit_cast(float, w[e] << 16);
                    float a1 = __builtin_bit_cast(float, w[e] & 0xffff0000u);
                    sp = fmaf(a0, sV[j], sp);
                    sp = fmaf(a1, sV[j + 1], sp);
                }
            }
            #pragma unroll
            for (int hh = 0; hh < 4; ++hh) {
                uint4 q = *(const uint4*)((const char*)bufB + m * 512 + ((p * 64 + hh * 16) ^ swz));
                uint32_t w[4] = {q.x, q.y, q.z, q.w};
                #pragma unroll
                for (int e = 0; e < 4; ++e) {
                    int j = p * 32 + hh * 8 + e * 2;
                    float a0 = __builtin_bit_cast(float, w[e] << 16);
                    float a1 = __builtin_bit_cast(float, w[e] & 0xffff0000u);
                    r0 = fmaf(a0, sR[j*3+0], r0); r1 = fmaf(a0, sR[j*3+1], r1); r2 = fmaf(a0, sR[j*3+2], r2);
                    r0 = fmaf(a1, sR[(j+1)*3+0], r0); r1 = fmaf(a1, sR[(j+1)*3+1], r1); r2 = fmaf(a1, sR[(j+1)*3+2], r2);
                }
            }
            #pragma unroll
            for (int off = 1; off < 4; off <<= 1) {
                sp += __shfl_xor(sp, off);
                r0 += __shfl_xor(r0, off);
                r1 += __shfl_xor(r1, off);
                r2 += __shfl_xor(r2, off);
            }
            if (p == 0 && gi < total) {
                float alpha = 1.0f - __expf(-fmaxf(sp, 0.0f) * STEPF);
                float c0 = 1.0f / (1.0f + __expf(-r0));
                float c1 = 1.0f / (1.0f + __expf(-r1));
                float c2 = 1.0f / (1.0f + __expf(-r2));
                rgbaL[gi] = make_float4(c0, c1, c2, alpha);
            }
        }
    }
    __syncthreads();

    // ---- phase 3: composite this wave's ray from LDS ----
    {
        float T_run = 1.0f;
        float cr = 0.f, cg = 0.f, cb = 0.f, opa = 0.f, dep = 0.f;
        for (int j = 0; j < myCnt; j += 64) {
            int idx = j + lane;
            float4 f = make_float4(0.f, 0.f, 0.f, 0.f);
            float tmid = 0.f;
            if (idx < myCnt) {
                f = rgbaL[myBase + idx];
                int s = sList[myBase + idx] & 255;
                tmid = (tn + STEPF * (float)s) + 0.5f * STEPF;
            }
            float p = (1.0f - f.w) + 1e-10f;
            #pragma unroll
            for (int o = 1; o < 64; o <<= 1) {
                float v = __shfl_up(p, o);
                if (lane >= o) p *= v;
            }
            float pprev = __shfl_up(p, 1);
            float Texc = (lane == 0) ? T_run : T_run * pprev;
            Texc = (Texc > ERTF) ? Texc : 0.0f;
            float w = Texc * f.w;
            cr += w * f.x; cg += w * f.y; cb += w * f.z;
            opa += w; dep += w * tmid;
            T_run *= __shfl(p, 63);
            if (T_run <= ERTF) break;   // exact: later exclusive-T <= ERT -> zero weight
        }
        #pragma unroll
        for (int o = 32; o; o >>= 1) {
            cr  += __shfl_xor(cr, o);
            cg  += __shfl_xor(cg, o);
            cb  += __shfl_xor(cb, o);
            opa += __shfl_xor(opa, o);
            dep += __shfl_xor(dep, o);
        }
        if (lane == 0) {
            out[r * 3 + 0] = cr + (1.0f - opa);
            out[r * 3 + 1] = cg + (1.0f - opa);
            out[r * 3 + 2] = cb + (1.0f - opa);
            out[NRAYS * 3 + r] = dep;            // depth
            out[NRAYS * 4 + r] = opa;            // opacity
        }
    }
}

extern "C" void kernel_launch(void* const* d_in, const int* in_sizes, int n_in,
                              void* d_out, int out_size, void* d_ws, size_t ws_size,
                              hipStream_t stream) {
    const float* ro   = (const float*)d_in[0];
    const float* rd   = (const float*)d_in[1];
    const int*   occ  = (const int*)d_in[2];
    const float* W0   = (const float*)d_in[3];
    const float* W1   = (const float*)d_in[4];
    const float* wsig = (const float*)d_in[5];
    const float* W2   = (const float*)d_in[6];
    const float* wrgb = (const float*)d_in[7];
    float* out = (float*)d_out;

    k_fused<<<NRAYS / 8, 512, 0, stream>>>(ro, rd, occ, W0, W1, wsig, W2, wrgb, out);
}